// Round 5
// baseline (1711.262 us; speedup 1.0000x reference)
//
#include <hip/hip_runtime.h>
#include <math.h>

#define LSEQ 1024
#define NB 16
#define NC 12
#define NH 256
#define NM 32
#define NS 3
#define TWO_PI 6.283185307179586f

// ---- workspace layout (float offsets) ----
#define OFF_MEANS 0            // 192
#define OFF_STDEV 192          // 192
#define OFF_EPART 384          // 24576
#define OFF_WT_RE 24960        // 24576
#define OFF_WT_IM 49536        // 24576
#define OFF_VP    74112        // 4*786432 = 3145728 (slice-last: [s][row][col][slice])
#define OFF_V     3219840      // 786432 (dense)
#define OFF_PP0   4006272      // 786432 (slice-last: [s][row][k][slice])
#define OFF_PP1   4792704      // 786432
#define OFF_H     5579136      // 1024
// total ~5.58M floats = 22.3 MB

__device__ __forceinline__ float block_reduce_sum(float v, float* sbuf) {
  int t = threadIdx.x;
  sbuf[t] = v; __syncthreads();
  for (int off = 128; off > 0; off >>= 1) {
    if (t < off) sbuf[t] += sbuf[t + off];
    __syncthreads();
  }
  float r = sbuf[0];
  __syncthreads();
  return r;
}

// front: stats (0..191) | epart (192..287) | Vp col0 init (288) | H/out init (289)
__global__ __launch_bounds__(256) void k_front(const float* __restrict__ x,
                                               const float* __restrict__ Bv,
                                               const float* __restrict__ ev,
                                               const float* __restrict__ b_fc,
                                               float* __restrict__ means,
                                               float* __restrict__ stdev,
                                               float* __restrict__ epart,
                                               float* __restrict__ Vp,
                                               float* __restrict__ H,
                                               float* __restrict__ out) {
  __shared__ float smem[1280];
  int blk = blockIdx.x;
  int t = threadIdx.x;
  if (blk < 192) {
    int b = blk / NC, c = blk % NC;
    float* xs = smem;
    float* red = smem + 1024;
    for (int e = 0; e < 4; ++e) {
      int tau = t + 256 * e;
      xs[tau] = x[((size_t)b * LSEQ + tau) * NC + c];
    }
    __syncthreads();
    float p = 0.f;
    for (int e = 0; e < 4; ++e) p += xs[t + 256 * e];
    float sum = block_reduce_sum(p, red);
    float mean = sum * (1.0f / LSEQ);
    float q = 0.f;
    for (int e = 0; e < 4; ++e) { float d = xs[t + 256 * e] - mean; q += d * d; }
    float sq = block_reduce_sum(q, red);
    if (t == 0) {
      means[blk] = mean;
      stdev[blk] = sqrtf(sq * (1.0f / LSEQ) + 1e-5f);
    }
  } else if (blk < 288) {
    int bb = blk - 192;          // s*32 + chunk
    int s = bb >> 5, ch = bb & 31;
    float acc = 0.f;
    const float* base = ev + (size_t)s * LSEQ * NH + (size_t)ch * 32 * NH + t;
    for (int l = 0; l < 32; ++l) acc += base[(size_t)l * NH];
    epart[(size_t)bb * NH + t] = acc;
  } else if (blk == 288) {
    // Vp[row][col=0][slice]: slice0 = B, others 0. 768 rows x 4 slices.
    for (int idx = t; idx < 768 * 4; idx += 256) {
      int row = idx >> 2, sl = idx & 3;
      Vp[(size_t)row * 4096 + sl] = (sl == 0) ? Bv[row] : 0.0f;
    }
  } else {
    for (int e = 0; e < 4; ++e) H[t + 256 * e] = 0.0f;
    if (t < NB * 5) out[t] = b_fc[t % 5];
  }
}

#define FMA_ROW(r, av) { acc[r][0] += (av)*b4.x; acc[r][1] += (av)*b4.y; acc[r][2] += (av)*b4.z; acc[r][3] += (av)*b4.w; }

// 128x64 output tile, single K=64 slice, full-tile prefetch (one barrier round).
// A: dense [row*256+k] if aDense, else slice-last float4 partials [(row*256+k)*4..]
// B: dense if bDense (row stride bldE), else slice-last float4 partials
// Output: slice-last scatter to outp[((row)*outldE + outcol0 + c)*4 + slice], c < colLimit
__device__ __forceinline__ void gemm64v2(float* As, float* Bs,
                                         const float* Ab, int aDense,
                                         const float* Bb, int bDense, int bldE,
                                         int colLimit,
                                         int rowbase, int colbase, int kb0,
                                         float* outp, int outldE, int outcol0,
                                         int slice) {
  const int tid = threadIdx.x;
  const int kkA = tid & 63, rA = tid >> 6;
  if (aDense) {
    #pragma unroll
    for (int p = 0; p < 32; ++p) {
      int row = rowbase + rA + 4 * p;
      As[kkA * 132 + rA + 4 * p] = Ab[(size_t)row * 256 + kb0 + kkA];
    }
  } else {
    #pragma unroll
    for (int p = 0; p < 32; ++p) {
      int row = rowbase + rA + 4 * p;
      float4 v = *(const float4*)(Ab + ((size_t)row * 256 + kb0 + kkA) * 4);
      As[kkA * 132 + rA + 4 * p] = (v.x + v.y) + (v.z + v.w);
    }
  }
  const int jB = tid & 63, kB = tid >> 6;
  const int j = colbase + jB;
  if (bDense) {
    #pragma unroll
    for (int q = 0; q < 16; ++q) {
      int kk = kB + 4 * q;
      Bs[kk * 68 + jB] = (j < colLimit) ? Bb[(size_t)(kb0 + kk) * bldE + j] : 0.0f;
    }
  } else {
    #pragma unroll
    for (int q = 0; q < 16; ++q) {
      int kk = kB + 4 * q;
      float v = 0.f;
      if (j < colLimit) {
        float4 u = *(const float4*)(Bb + ((size_t)(kb0 + kk) * bldE + j) * 4);
        v = (u.x + u.y) + (u.z + u.w);
      }
      Bs[kk * 68 + jB] = v;
    }
  }
  __syncthreads();
  const int tx = tid & 15, ty = tid >> 4;
  float acc[8][4];
  #pragma unroll
  for (int i = 0; i < 8; ++i)
    #pragma unroll
    for (int jj = 0; jj < 4; ++jj) acc[i][jj] = 0.f;
  #pragma unroll
  for (int kk = 0; kk < 64; ++kk) {
    float4 b4 = *(const float4*)(Bs + kk * 68 + tx * 4);
    float4 a0 = *(const float4*)(As + kk * 132 + ty * 8);
    float4 a1 = *(const float4*)(As + kk * 132 + ty * 8 + 4);
    FMA_ROW(0, a0.x) FMA_ROW(1, a0.y) FMA_ROW(2, a0.z) FMA_ROW(3, a0.w)
    FMA_ROW(4, a1.x) FMA_ROW(5, a1.y) FMA_ROW(6, a1.z) FMA_ROW(7, a1.w)
  }
  #pragma unroll
  for (int i = 0; i < 8; ++i) {
    int row = rowbase + ty * 8 + i;
    #pragma unroll
    for (int jj = 0; jj < 4; ++jj) {
      int c = colbase + tx * 4 + jj;
      if (c < colLimit)
        outp[((size_t)row * outldE + outcol0 + c) * 4 + slice] = acc[i][jj];
    }
  }
}

__device__ void wtilde_task(int w, float* smem, const float* wre, const float* wim,
                            const float* epart, float* wt_re, float* wt_im) {
  int s = w >> 8, i = w & 255;
  int t = threadIdx.x;
  float* ebs = smem;
  float* sr = smem + 256;
  float* si2 = smem + 512;
  float eb = 0.f;
  for (int chk = 0; chk < 32; ++chk) eb += epart[(s * 32 + chk) * 256 + t];
  ebs[t] = eb * (1.0f / LSEQ);
  __syncthreads();
  const float* br = wre + (size_t)(s * NH + i) * NH * NM;
  const float* bi = wim + (size_t)(s * NH + i) * NH * NM;
  float accR = 0.f, accI = 0.f;
  int g = t >> 5;
  for (int it = 0; it < 32; ++it) {
    int o = g + 8 * it;
    float e = ebs[o];
    int idx = t + 256 * it;   // == o*32 + k, coalesced
    accR += e * br[idx];
    accI += e * bi[idx];
  }
  sr[t] = accR; si2[t] = accI;
  __syncthreads();
  if (t < 32) {
    float aR = 0.f, aI = 0.f;
    for (int gg = 0; gg < 8; ++gg) { aR += sr[gg * 32 + t]; aI += si2[gg * 32 + t]; }
    wt_re[(size_t)(s * NM + t) * NH + i] = aR;
    wt_im[(size_t)(s * NM + t) * NH + i] = aI;
  }
  __syncthreads();
}

// one chain stage: squares (split-K4, slice-last partials) | extends (split-K4, slice-last) | wtilde filler
__global__ __launch_bounds__(256) void k_chain(const float* __restrict__ Pc,
                                               float* __restrict__ Pn,
                                               float* __restrict__ Vp,
                                               const float* __restrict__ wre,
                                               const float* __restrict__ wim,
                                               const float* __restrict__ epart,
                                               float* __restrict__ wt_re,
                                               float* __restrict__ wt_im,
                                               int m, int aDense, int nSq, int ntct,
                                               int wstart) {
  __shared__ float smem[12800];   // As 64x132 (8448) + Bs 64x68 (4352) = 51.2 KB
  float* As = smem;
  float* Bs = smem + 8448;
  const int blk = blockIdx.x;
  const int nExt = 24 * ntct;
  if (blk < nSq) {
    int slice = blk & 3, rest = blk >> 2;
    int t8 = rest & 7, s = rest >> 3;
    int rt = t8 & 1, ct = t8 >> 1;              // ct < 4
    const float* Ab = Pc + (size_t)s * (aDense ? 65536 : 262144);
    gemm64v2(As, Bs, Ab, aDense, Ab, 0 /*bDense only if aDense*/ | aDense, 256, 256,
             rt * 128, ct * 64, slice * 64,
             Pn + (size_t)s * 262144, 256, 0, slice);
  } else if (blk < nSq + nExt) {
    int e = blk - nSq;
    int slice = e & 3, rt = (e >> 2) & 1, rest2 = e >> 3;
    int ct = rest2 % ntct, s = rest2 / ntct;
    const float* Ab = Pc + (size_t)s * (aDense ? 65536 : 262144);
    gemm64v2(As, Bs, Ab, aDense, Vp + (size_t)s * 1048576, 0, 1024, m,
             rt * 128, ct * 64, slice * 64,
             Vp + (size_t)s * 1048576, 1024, m, slice);
  } else {
    int w = wstart + (blk - nSq - nExt);
    if (w < NS * NH) wtilde_task(w, smem, wre, wim, epart, wt_re, wt_im);
  }
}

// collapse Vp (4 slices) -> dense V
__global__ __launch_bounds__(256) void k_reduceV(const float* __restrict__ Vp,
                                                 float* __restrict__ V) {
  int t = threadIdx.x;
  size_t base = (size_t)blockIdx.x * 1024;
  for (int e = 0; e < 4; ++e) {
    size_t idx = base + e * 256 + t;
    float4 u = *(const float4*)(Vp + idx * 4);
    V[idx] = (u.x + u.y) + (u.z + u.w);
  }
}

// fused: ut row (s,k) -> twiddle -> in-LDS prefix scan -> atomic H contribution
__global__ __launch_bounds__(256) void k_utscan(const float* __restrict__ wt_re,
                                                const float* __restrict__ wt_im,
                                                const float* __restrict__ V,
                                                const float* __restrict__ w_mlp,
                                                float* __restrict__ H) {
  int blk = blockIdx.x;   // s*NM + k
  int s = blk / NM, k = blk & 31;
  int t = threadIdx.x;
  __shared__ float sr[LSEQ], si_[LSEQ];
  __shared__ float cr[256], ci[256];
  const float* wr = wt_re + (size_t)blk * NH;
  const float* wi_ = wt_im + (size_t)blk * NH;
  const float* Vs = V + (size_t)s * NH * LSEQ;
  float ar[4] = {0.f, 0.f, 0.f, 0.f}, ai[4] = {0.f, 0.f, 0.f, 0.f};
  for (int i = 0; i < NH; ++i) {
    float a = wr[i], b = wi_[i];
    const float* vrow = Vs + (size_t)i * LSEQ + t;
    #pragma unroll
    for (int e = 0; e < 4; ++e) {
      float v = vrow[256 * e];
      ar[e] += a * v; ai[e] += b * v;
    }
  }
  for (int e = 0; e < 4; ++e) {
    int d = t + 256 * e;
    int frac = (k * d) & 1023;
    float ang = -(TWO_PI / 1024.0f) * (float)frac;
    float sn, csn; sincosf(ang, &sn, &csn);
    sr[d] = ar[e] * csn - ai[e] * sn;
    si_[d] = ar[e] * sn + ai[e] * csn;
  }
  __syncthreads();
  float lr[4], li[4], rr = 0.f, ii = 0.f;
  for (int e = 0; e < 4; ++e) {
    rr += sr[4 * t + e]; ii += si_[4 * t + e];
    lr[e] = rr; li[e] = ii;
  }
  cr[t] = rr; ci[t] = ii;
  __syncthreads();
  for (int off = 1; off < 256; off <<= 1) {
    float pr = 0.f, pi = 0.f;
    if (t >= off) { pr = cr[t - off]; pi = ci[t - off]; }
    __syncthreads();
    cr[t] += pr; ci[t] += pi;
    __syncthreads();
  }
  float offr = (t > 0) ? cr[t - 1] : 0.0f;
  float offi = (t > 0) ? ci[t - 1] : 0.0f;
  for (int e = 0; e < 4; ++e) {
    sr[4 * t + e] = lr[e] + offr;
    si_[4 * t + e] = li[e] + offi;
  }
  __syncthreads();
  float wm = w_mlp[s];
  float coef = wm * ((k == 0) ? 1.0f : 2.0f) * (1.0f / LSEQ);
  for (int e = 0; e < 4; ++e) {
    int tau = t + 256 * e;
    int mIdx = 1023 - tau;
    int frac = (k * (tau + 1)) & 1023;
    float ang = -(TWO_PI / 1024.0f) * (float)frac;
    float sn, csn; sincosf(ang, &sn, &csn);
    float val = coef * (sr[mIdx] * csn - si_[mIdx] * sn);
    atomicAdd(&H[tau], val);
  }
}

// feat per (b,c) + atomic accumulate into out (pre-initialized to b_fc)
__global__ __launch_bounds__(256) void k_feat(const float* __restrict__ x,
                                              const float* __restrict__ means,
                                              const float* __restrict__ stdev,
                                              const float* __restrict__ aw,
                                              const float* __restrict__ ab,
                                              const float* __restrict__ b_mlp,
                                              const float* __restrict__ H,
                                              const float* __restrict__ w_fc,
                                              float* __restrict__ out) {
  int bc = blockIdx.x; int b = bc / NC, c = bc % NC;
  __shared__ float red[256];
  int t = threadIdx.x;
  float mn = means[bc], sd = stdev[bc];
  float w = aw[c], bb = ab[c];
  float acc = 0.f;
  for (int e = 0; e < 4; ++e) {
    int tau = t + 256 * e;
    float xv = x[((size_t)b * LSEQ + tau) * NC + c];
    float f = (xv - mn) / sd * w + bb;
    acc += f * H[tau];
  }
  float sum = block_reduce_sum(acc, red);
  if (t == 0) {
    float mr = sum + b_mlp[0];
    float featv = (mr - bb) / (w + 1e-10f) * sd + mn;
    #pragma unroll
    for (int d = 0; d < 5; ++d)
      atomicAdd(&out[b * 5 + d], featv * w_fc[d * NC + c]);
  }
}

extern "C" void kernel_launch(void* const* d_in, const int* in_sizes, int n_in,
                              void* d_out, int out_size, void* d_ws, size_t ws_size,
                              hipStream_t stream) {
  const float* x_enc   = (const float*)d_in[0];
  const float* aw      = (const float*)d_in[1];
  const float* ab      = (const float*)d_in[2];
  const float* wre     = (const float*)d_in[3];
  const float* wim     = (const float*)d_in[4];
  const float* w_mlp   = (const float*)d_in[5];
  const float* b_mlp   = (const float*)d_in[6];
  const float* w_fc    = (const float*)d_in[7];
  const float* b_fc    = (const float*)d_in[8];
  const float* A_mats  = (const float*)d_in[9];
  const float* B_vecs  = (const float*)d_in[10];
  const float* ev      = (const float*)d_in[11];

  float* ws    = (float*)d_ws;
  float* means = ws + OFF_MEANS;
  float* stdev = ws + OFF_STDEV;
  float* epart = ws + OFF_EPART;
  float* wt_re = ws + OFF_WT_RE;
  float* wt_im = ws + OFF_WT_IM;
  float* Vp    = ws + OFF_VP;
  float* V     = ws + OFF_V;
  float* PP0   = ws + OFF_PP0;
  float* PP1   = ws + OFF_PP1;
  float* H     = ws + OFF_H;
  float* out   = (float*)d_out;

  k_front<<<290, 256, 0, stream>>>(x_enc, B_vecs, ev, b_fc, means, stdev, epart, Vp, H, out);

  const float* Pc = A_mats; int aDense = 1;
  float* Pn = PP0;
  for (int si = 0; si < 10; ++si) {
    int m = 1 << si;
    int doSq = (si < 9);
    int nSq = doSq ? 96 : 0;
    int ntct = (m + 63) >> 6;
    int nFill = (si < 5) ? 154 : 0;
    int grid = nSq + 24 * ntct + nFill;
    k_chain<<<grid, 256, 0, stream>>>(Pc, Pn, Vp, wre, wim, epart, wt_re, wt_im,
                                      m, aDense, nSq, ntct, si * 154);
    if (doSq) { Pc = Pn; aDense = 0; Pn = (Pn == PP0) ? PP1 : PP0; }
  }

  k_reduceV<<<768, 256, 0, stream>>>(Vp, V);
  k_utscan<<<NS * NM, 256, 0, stream>>>(wt_re, wt_im, V, w_mlp, H);
  k_feat<<<192, 256, 0, stream>>>(x_enc, means, stdev, aw, ab, b_mlp, H, w_fc, out);
}

// Round 6
// 573.664 us; speedup vs baseline: 2.9830x; 2.9830x over previous
//
#include <hip/hip_runtime.h>
#include <math.h>

#define LSEQ 1024
#define NB 16
#define NC 12
#define NH 256
#define NM 32
#define NS 3
#define TWO_PI 6.283185307179586f

#define PSTR  196608     // P plane stride (3*256*256)
#define VPSTR 786432     // V plane stride (3*256*1024)

// ---- workspace layout (float offsets) ----
#define OFF_MEANS 0            // 192
#define OFF_STDEV 192          // 192
#define OFF_EPART 384          // 24576
#define OFF_WT_RE 24960        // 24576
#define OFF_WT_IM 49536        // 24576
#define OFF_VP    74112        // 4 planes x 786432 = 3145728
#define OFF_V     3219840      // 786432 (dense)
#define OFF_PP0   4006272      // 786432 (4 planes x 196608)
#define OFF_PP1   4792704      // 786432
#define OFF_H     5579136      // 1024
// total ~5.58M floats = 22.3 MB

__device__ __forceinline__ float block_reduce_sum(float v, float* sbuf) {
  int t = threadIdx.x;
  sbuf[t] = v; __syncthreads();
  for (int off = 128; off > 0; off >>= 1) {
    if (t < off) sbuf[t] += sbuf[t + off];
    __syncthreads();
  }
  float r = sbuf[0];
  __syncthreads();
  return r;
}

// front: stats (0..191) | epart (192..287) | Vp col0 init (288) | H/out init (289)
__global__ __launch_bounds__(256) void k_front(const float* __restrict__ x,
                                               const float* __restrict__ Bv,
                                               const float* __restrict__ ev,
                                               const float* __restrict__ b_fc,
                                               float* __restrict__ means,
                                               float* __restrict__ stdev,
                                               float* __restrict__ epart,
                                               float* __restrict__ Vp,
                                               float* __restrict__ H,
                                               float* __restrict__ out) {
  __shared__ float smem[1280];
  int blk = blockIdx.x;
  int t = threadIdx.x;
  if (blk < 192) {
    int b = blk / NC, c = blk % NC;
    float* xs = smem;
    float* red = smem + 1024;
    for (int e = 0; e < 4; ++e) {
      int tau = t + 256 * e;
      xs[tau] = x[((size_t)b * LSEQ + tau) * NC + c];
    }
    __syncthreads();
    float p = 0.f;
    for (int e = 0; e < 4; ++e) p += xs[t + 256 * e];
    float sum = block_reduce_sum(p, red);
    float mean = sum * (1.0f / LSEQ);
    float q = 0.f;
    for (int e = 0; e < 4; ++e) { float d = xs[t + 256 * e] - mean; q += d * d; }
    float sq = block_reduce_sum(q, red);
    if (t == 0) {
      means[blk] = mean;
      stdev[blk] = sqrtf(sq * (1.0f / LSEQ) + 1e-5f);
    }
  } else if (blk < 288) {
    int bb = blk - 192;          // s*32 + chunk
    int s = bb >> 5, ch = bb & 31;
    float acc = 0.f;
    const float* base = ev + (size_t)s * LSEQ * NH + (size_t)ch * 32 * NH + t;
    for (int l = 0; l < 32; ++l) acc += base[(size_t)l * NH];
    epart[(size_t)bb * NH + t] = acc;
  } else if (blk == 288) {
    // col 0 of each plane: plane0 = B, planes 1-3 = 0 (other cols written by chain stages)
    for (int idx = t; idx < 768 * 4; idx += 256) {
      int row = idx & 767, pl = idx >> 9;   // note: covers all (row,plane) pairs? no —
    }
    // explicit: 4 planes x 768 rows
    for (int pl = 0; pl < 4; ++pl)
      for (int row = t; row < 768; row += 256)
        Vp[(size_t)pl * VPSTR + (size_t)row * LSEQ] = (pl == 0) ? Bv[row] : 0.0f;
  } else {
    for (int e = 0; e < 4; ++e) H[t + 256 * e] = 0.0f;
    if (t < NB * 5) out[t] = b_fc[t % 5];
  }
}

#define FMA_ROW(r, av) { acc[r][0] += (av)*b4.x; acc[r][1] += (av)*b4.y; acc[r][2] += (av)*b4.z; acc[r][3] += (av)*b4.w; }

// 128x64 output tile, K-slice of 64 (2 chunks of 32). 256 threads, 8x4 acc/thread.
// A/B inputs may be carried as plane-partials (anp/bnp planes, stride apstr/bpstr) summed during staging.
// Output written densely (no atomics) to outp; caller points outp at the target plane.
__device__ void gemm64(float* As, float* Bs,
                       const float* Abase, int anp, int apstr,
                       const float* Bbase, int bnp, int bpstr, int bld, int colLimit,
                       int rowbase, int colbase, int kb0,
                       float* outp, int outld, int outcol0, int outColLim) {
  const int tid = threadIdx.x;
  const int tx = tid & 15, ty = tid >> 4;
  const int kkA = tid & 31, rA = tid >> 5;
  const int jB = tid & 63, kB = tid >> 6;
  float acc[8][4];
  #pragma unroll
  for (int i = 0; i < 8; ++i)
    #pragma unroll
    for (int j = 0; j < 4; ++j) acc[i][j] = 0.f;

  for (int ch = 0; ch < 2; ++ch) {
    int kb = kb0 + ch * 32;
    #pragma unroll
    for (int p = 0; p < 16; ++p) {
      int row = rowbase + rA + 8 * p;
      float v = 0.f;
      for (int pp = 0; pp < anp; ++pp) v += Abase[(size_t)pp * apstr + (size_t)row * 256 + kb + kkA];
      As[kkA * 132 + rA + 8 * p] = v;
    }
    #pragma unroll
    for (int q = 0; q < 8; ++q) {
      int kk = kB + 4 * q;
      int j = colbase + jB;
      float v = 0.f;
      if (j < colLimit) {
        for (int pp = 0; pp < bnp; ++pp) v += Bbase[(size_t)pp * bpstr + (size_t)(kb + kk) * bld + j];
      }
      Bs[kk * 68 + jB] = v;
    }
    __syncthreads();
    #pragma unroll
    for (int kk = 0; kk < 32; ++kk) {
      float4 b4 = *(const float4*)(Bs + kk * 68 + tx * 4);
      float4 a0 = *(const float4*)(As + kk * 132 + ty * 8);
      float4 a1 = *(const float4*)(As + kk * 132 + ty * 8 + 4);
      FMA_ROW(0, a0.x) FMA_ROW(1, a0.y) FMA_ROW(2, a0.z) FMA_ROW(3, a0.w)
      FMA_ROW(4, a1.x) FMA_ROW(5, a1.y) FMA_ROW(6, a1.z) FMA_ROW(7, a1.w)
    }
    __syncthreads();
  }
  if (colbase + 64 <= outColLim) {
    #pragma unroll
    for (int i = 0; i < 8; ++i) {
      int row = rowbase + ty * 8 + i;
      float4 st; st.x = acc[i][0]; st.y = acc[i][1]; st.z = acc[i][2]; st.w = acc[i][3];
      *(float4*)(outp + (size_t)row * outld + outcol0 + colbase + tx * 4) = st;
    }
  } else {
    #pragma unroll
    for (int i = 0; i < 8; ++i) {
      int row = rowbase + ty * 8 + i;
      #pragma unroll
      for (int j = 0; j < 4; ++j) {
        int c = colbase + tx * 4 + j;
        if (c < outColLim) outp[(size_t)row * outld + outcol0 + c] = acc[i][j];
      }
    }
  }
}

__device__ void wtilde_task(int w, float* smem, const float* wre, const float* wim,
                            const float* epart, float* wt_re, float* wt_im) {
  int s = w >> 8, i = w & 255;
  int t = threadIdx.x;
  float* ebs = smem;
  float* sr = smem + 256;
  float* si2 = smem + 512;
  float eb = 0.f;
  for (int chk = 0; chk < 32; ++chk) eb += epart[(s * 32 + chk) * 256 + t];
  ebs[t] = eb * (1.0f / LSEQ);
  __syncthreads();
  const float* br = wre + (size_t)(s * NH + i) * NH * NM;
  const float* bi = wim + (size_t)(s * NH + i) * NH * NM;
  float accR = 0.f, accI = 0.f;
  int g = t >> 5;
  for (int it = 0; it < 32; ++it) {
    int o = g + 8 * it;
    float e = ebs[o];
    int idx = t + 256 * it;   // == o*32 + k, coalesced
    accR += e * br[idx];
    accI += e * bi[idx];
  }
  sr[t] = accR; si2[t] = accI;
  __syncthreads();
  if (t < 32) {
    float aR = 0.f, aI = 0.f;
    for (int gg = 0; gg < 8; ++gg) { aR += sr[gg * 32 + t]; aI += si2[gg * 32 + t]; }
    wt_re[(size_t)(s * NM + t) * NH + i] = aR;
    wt_im[(size_t)(s * NM + t) * NH + i] = aI;
  }
  __syncthreads();
}

// one chain stage: squares (split-K4 -> P planes) | extends (split-K4 -> V planes) | wtilde filler
__global__ __launch_bounds__(256) void k_chain(const float* __restrict__ Pc,
                                               float* __restrict__ Pn,
                                               float* __restrict__ Vp,
                                               const float* __restrict__ wre,
                                               const float* __restrict__ wim,
                                               const float* __restrict__ epart,
                                               float* __restrict__ wt_re,
                                               float* __restrict__ wt_im,
                                               int m, int anp, int nSq, int ntct,
                                               int wstart) {
  __shared__ float smem[6608];
  float* As = smem;            // [32][132]
  float* Bs = smem + 4224;     // [32][68]
  const int blk = blockIdx.x;
  const int nExt = 24 * ntct;
  if (blk < nSq) {
    int slice = blk & 3, rest = blk >> 2;
    int t8 = rest & 7, s = rest >> 3;
    int rt = t8 & 1, ct = t8 >> 1;
    const float* Ab = Pc + (size_t)s * 65536;
    gemm64(As, Bs, Ab, anp, PSTR, Ab, anp, PSTR, 256, 256,
           rt * 128, ct * 64, slice * 64,
           Pn + (size_t)slice * PSTR + (size_t)s * 65536, 256, 0, 256);
  } else if (blk < nSq + nExt) {
    int e = blk - nSq;
    int slice = e & 3, rt = (e >> 2) & 1, rest2 = e >> 3;
    int ct = rest2 % ntct, s = rest2 / ntct;
    gemm64(As, Bs, Pc + (size_t)s * 65536, anp, PSTR,
           Vp + (size_t)s * 262144, 4, VPSTR, 1024, m,
           rt * 128, ct * 64, slice * 64,
           Vp + (size_t)slice * VPSTR + (size_t)s * 262144, 1024, m, m);
  } else {
    int w = wstart + (blk - nSq - nExt);
    if (w < NS * NH) wtilde_task(w, smem, wre, wim, epart, wt_re, wt_im);
  }
}

// collapse 4 V planes -> dense V
__global__ __launch_bounds__(256) void k_reduceV(const float* __restrict__ Vp,
                                                 float* __restrict__ V) {
  int t = threadIdx.x;
  size_t base = (size_t)blockIdx.x * 1024;
  for (int e = 0; e < 4; ++e) {
    size_t idx = base + e * 256 + t;
    V[idx] = (Vp[idx] + Vp[VPSTR + idx]) + (Vp[2 * VPSTR + idx] + Vp[3 * VPSTR + idx]);
  }
}

// fused: ut row (s,k) -> twiddle -> in-LDS prefix scan -> atomic H contribution
__global__ __launch_bounds__(256) void k_utscan(const float* __restrict__ wt_re,
                                                const float* __restrict__ wt_im,
                                                const float* __restrict__ V,
                                                const float* __restrict__ w_mlp,
                                                float* __restrict__ H) {
  int blk = blockIdx.x;   // s*NM + k
  int s = blk / NM, k = blk & 31;
  int t = threadIdx.x;
  __shared__ float sr[LSEQ], si_[LSEQ];
  __shared__ float cr[256], ci[256];
  const float* wr = wt_re + (size_t)blk * NH;
  const float* wi_ = wt_im + (size_t)blk * NH;
  const float* Vs = V + (size_t)s * NH * LSEQ;
  float ar[4] = {0.f, 0.f, 0.f, 0.f}, ai[4] = {0.f, 0.f, 0.f, 0.f};
  for (int i = 0; i < NH; ++i) {
    float a = wr[i], b = wi_[i];
    const float* vrow = Vs + (size_t)i * LSEQ + t;
    #pragma unroll
    for (int e = 0; e < 4; ++e) {
      float v = vrow[256 * e];
      ar[e] += a * v; ai[e] += b * v;
    }
  }
  for (int e = 0; e < 4; ++e) {
    int d = t + 256 * e;
    int frac = (k * d) & 1023;
    float ang = -(TWO_PI / 1024.0f) * (float)frac;
    float sn, csn; sincosf(ang, &sn, &csn);
    sr[d] = ar[e] * csn - ai[e] * sn;
    si_[d] = ar[e] * sn + ai[e] * csn;
  }
  __syncthreads();
  float lr[4], li[4], rr = 0.f, ii = 0.f;
  for (int e = 0; e < 4; ++e) {
    rr += sr[4 * t + e]; ii += si_[4 * t + e];
    lr[e] = rr; li[e] = ii;
  }
  cr[t] = rr; ci[t] = ii;
  __syncthreads();
  for (int off = 1; off < 256; off <<= 1) {
    float pr = 0.f, pi = 0.f;
    if (t >= off) { pr = cr[t - off]; pi = ci[t - off]; }
    __syncthreads();
    cr[t] += pr; ci[t] += pi;
    __syncthreads();
  }
  float offr = (t > 0) ? cr[t - 1] : 0.0f;
  float offi = (t > 0) ? ci[t - 1] : 0.0f;
  for (int e = 0; e < 4; ++e) {
    sr[4 * t + e] = lr[e] + offr;
    si_[4 * t + e] = li[e] + offi;
  }
  __syncthreads();
  float wm = w_mlp[s];
  float coef = wm * ((k == 0) ? 1.0f : 2.0f) * (1.0f / LSEQ);
  for (int e = 0; e < 4; ++e) {
    int tau = t + 256 * e;
    int mIdx = 1023 - tau;
    int frac = (k * (tau + 1)) & 1023;
    float ang = -(TWO_PI / 1024.0f) * (float)frac;
    float sn, csn; sincosf(ang, &sn, &csn);
    float val = coef * (sr[mIdx] * csn - si_[mIdx] * sn);
    atomicAdd(&H[tau], val);
  }
}

// feat per (b,c) + atomic accumulate into out (pre-initialized to b_fc)
__global__ __launch_bounds__(256) void k_feat(const float* __restrict__ x,
                                              const float* __restrict__ means,
                                              const float* __restrict__ stdev,
                                              const float* __restrict__ aw,
                                              const float* __restrict__ ab,
                                              const float* __restrict__ b_mlp,
                                              const float* __restrict__ H,
                                              const float* __restrict__ w_fc,
                                              float* __restrict__ out) {
  int bc = blockIdx.x; int b = bc / NC, c = bc % NC;
  __shared__ float red[256];
  int t = threadIdx.x;
  float mn = means[bc], sd = stdev[bc];
  float w = aw[c], bb = ab[c];
  float acc = 0.f;
  for (int e = 0; e < 4; ++e) {
    int tau = t + 256 * e;
    float xv = x[((size_t)b * LSEQ + tau) * NC + c];
    float f = (xv - mn) / sd * w + bb;
    acc += f * H[tau];
  }
  float sum = block_reduce_sum(acc, red);
  if (t == 0) {
    float mr = sum + b_mlp[0];
    float featv = (mr - bb) / (w + 1e-10f) * sd + mn;
    #pragma unroll
    for (int d = 0; d < 5; ++d)
      atomicAdd(&out[b * 5 + d], featv * w_fc[d * NC + c]);
  }
}

extern "C" void kernel_launch(void* const* d_in, const int* in_sizes, int n_in,
                              void* d_out, int out_size, void* d_ws, size_t ws_size,
                              hipStream_t stream) {
  const float* x_enc   = (const float*)d_in[0];
  const float* aw      = (const float*)d_in[1];
  const float* ab      = (const float*)d_in[2];
  const float* wre     = (const float*)d_in[3];
  const float* wim     = (const float*)d_in[4];
  const float* w_mlp   = (const float*)d_in[5];
  const float* b_mlp   = (const float*)d_in[6];
  const float* w_fc    = (const float*)d_in[7];
  const float* b_fc    = (const float*)d_in[8];
  const float* A_mats  = (const float*)d_in[9];
  const float* B_vecs  = (const float*)d_in[10];
  const float* ev      = (const float*)d_in[11];

  float* ws    = (float*)d_ws;
  float* means = ws + OFF_MEANS;
  float* stdev = ws + OFF_STDEV;
  float* epart = ws + OFF_EPART;
  float* wt_re = ws + OFF_WT_RE;
  float* wt_im = ws + OFF_WT_IM;
  float* Vp    = ws + OFF_VP;
  float* V     = ws + OFF_V;
  float* PP0   = ws + OFF_PP0;
  float* PP1   = ws + OFF_PP1;
  float* H     = ws + OFF_H;
  float* out   = (float*)d_out;

  k_front<<<290, 256, 0, stream>>>(x_enc, B_vecs, ev, b_fc, means, stdev, epart, Vp, H, out);

  const float* Pc = A_mats; int anp = 1;
  float* Pn = PP0;
  for (int si = 0; si < 10; ++si) {
    int m = 1 << si;
    int doSq = (si < 9);
    int nSq = doSq ? 96 : 0;
    int ntct = (m + 63) >> 6;
    int nFill = (si < 5) ? 154 : 0;
    int grid = nSq + 24 * ntct + nFill;
    k_chain<<<grid, 256, 0, stream>>>(Pc, Pn, Vp, wre, wim, epart, wt_re, wt_im,
                                      m, anp, nSq, ntct, si * 154);
    if (doSq) { Pc = Pn; anp = 4; Pn = (Pn == PP0) ? PP1 : PP0; }
  }

  k_reduceV<<<768, 256, 0, stream>>>(Vp, V);
  k_utscan<<<NS * NM, 256, 0, stream>>>(wt_re, wt_im, V, w_mlp, H);
  k_feat<<<192, 256, 0, stream>>>(x_enc, means, stdev, aw, ab, b_mlp, H, w_fc, out);
}